// Round 4
// 1781.183 us; speedup vs baseline: 1.0035x; 1.0035x over previous
//
#include <hip/hip_runtime.h>

typedef unsigned short u16;
typedef __bf16 bf16x8 __attribute__((ext_vector_type(8)));
typedef float f32x4 __attribute__((ext_vector_type(4)));

__device__ __forceinline__ u16 f2bf(float f) {
  unsigned u = __builtin_bit_cast(unsigned, f);
  u += 0x7FFFu + ((u >> 16) & 1u);   // round-to-nearest-even
  return (u16)(u >> 16);
}
__device__ __forceinline__ float bf2f(u16 h) {
  unsigned u = ((unsigned)h) << 16;
  return __builtin_bit_cast(float, u);
}

// ---------------------------------------------------------------------------
// GEMM: C[M,N] = scale * (A[M,K] @ Bt[N,K]^T) (+resid) (relu) ; A,Bt bf16.
// 128x128 tile, BK=32, 256 threads (4 waves, 2x2), mfma_f32_16x16x32_bf16.
// Staging via global_load_lds width=16 (m97 structure).
// Batched over blockIdx.z with element strides sA,sB,sC.
// XCD-chunked bijective swizzle (m204) + M-fastest tile order: each XCD owns
// a contiguous run of tiles and sweeps all M-tiles of one B column-panel
// back-to-back, so the 512KB B panel is L2-resident and B streams from
// HBM/LLC ~once instead of once per M-row sweep.
// ---------------------------------------------------------------------------
template <bool OUT_BF16, bool RELU, bool RESID>
__global__ __launch_bounds__(256)
void gemm_bt(const u16* __restrict__ A, const u16* __restrict__ Bt,
             void* __restrict__ Cout, const float* __restrict__ resid,
             float scale, int M, int N, int K,
             int lda, int ldb, int ldc,
             long long sA, long long sB, long long sC)
{
  __shared__ u16 As[128 * 32];
  __shared__ u16 Bs[128 * 32];

  const int tid = threadIdx.x;
  const int z   = blockIdx.z;

  // --- XCD-aware bijective remap (m204), then decompose M-fastest ---
  const int gx = gridDim.x, gy = gridDim.y;
  const int nwg = gx * gy;
  const int orig = blockIdx.y * gx + blockIdx.x;
  const int q   = nwg >> 3, r = nwg & 7;
  const int xcd = orig & 7, ix = orig >> 3;
  const int wg  = ((xcd < r) ? xcd * (q + 1) : r * (q + 1) + (xcd - r) * q) + ix;
  const int m0  = (wg % gy) * 128;   // M varies fastest within an XCD chunk
  const int n0  = (wg / gy) * 128;

  const u16* pA = A + (size_t)z * sA + (size_t)m0 * lda;
  const u16* pB = Bt + (size_t)z * sB + (size_t)n0 * ldb;

  const int lane = tid & 63;
  const int w    = tid >> 6;
  const int wm   = w & 1;
  const int wn   = w >> 1;
  const int l16  = lane & 15;
  const int quad = lane >> 4;

  f32x4 acc[4][4] = {};

  for (int k0 = 0; k0 < K; k0 += 32) {
    // --- stage A/B tiles: 8 KB each = 512 chunks of 16B, 2 rounds of 256 thr
#pragma unroll
    for (int rr = 0; rr < 2; ++rr) {
      int c   = tid + 256 * rr;
      int row = c >> 2;            // 0..127
      int col = (c & 3) << 3;      // 0,8,16,24 (bf16 elems)
      __builtin_amdgcn_global_load_lds(
          (__attribute__((address_space(1))) void*)(pA + (size_t)row * lda + k0 + col),
          (__attribute__((address_space(3))) void*)(As + (size_t)c * 8), 16, 0, 0);
      __builtin_amdgcn_global_load_lds(
          (__attribute__((address_space(1))) void*)(pB + (size_t)row * ldb + k0 + col),
          (__attribute__((address_space(3))) void*)(Bs + (size_t)c * 8), 16, 0, 0);
    }
    __syncthreads();

    bf16x8 af[4], bf_[4];
#pragma unroll
    for (int i = 0; i < 4; ++i) {
      af[i]  = *(const bf16x8*)(As + (wm * 64 + i * 16 + l16) * 32 + quad * 8);
      bf_[i] = *(const bf16x8*)(Bs + (wn * 64 + i * 16 + l16) * 32 + quad * 8);
    }
#pragma unroll
    for (int mi = 0; mi < 4; ++mi)
#pragma unroll
      for (int ni = 0; ni < 4; ++ni)
        acc[mi][ni] = __builtin_amdgcn_mfma_f32_16x16x32_bf16(af[mi], bf_[ni], acc[mi][ni], 0, 0, 0);
    __syncthreads();
  }

  // --- epilogue. C/D layout: col = lane&15, row = quad*4 + reg (m89/m91).
  const size_t cbase = (size_t)z * sC;
#pragma unroll
  for (int mi = 0; mi < 4; ++mi) {
#pragma unroll
    for (int ni = 0; ni < 4; ++ni) {
      int col = n0 + wn * 64 + ni * 16 + l16;
#pragma unroll
      for (int rr = 0; rr < 4; ++rr) {
        int row = m0 + wm * 64 + mi * 16 + quad * 4 + rr;
        float v = acc[mi][ni][rr] * scale;
        if (RELU) v = fmaxf(v, 0.0f);
        size_t idx = cbase + (size_t)row * ldc + col;
        if (RESID) v += resid[idx];
        if (OUT_BF16) ((u16*)Cout)[idx] = f2bf(v);
        else          ((float*)Cout)[idx] = v;
      }
    }
  }
}

// ---------------------------------------------------------------------------
// Weight convert+transpose: in f32 [K,N] -> out bf16 [N,K]. 64x64 tiles.
// ---------------------------------------------------------------------------
__global__ __launch_bounds__(256)
void wtrans(const float* __restrict__ in, u16* __restrict__ out, int K, int N)
{
  __shared__ float t[64][65];
  const int k0 = blockIdx.y * 64;
  const int n0 = blockIdx.x * 64;
  const int tid = threadIdx.x;
  const int r  = tid >> 4;          // 0..15
  const int c4 = (tid & 15) * 4;    // 0..60
#pragma unroll
  for (int i = 0; i < 4; ++i) {
    int row = r + i * 16;
    float4 v = *(const float4*)(in + (size_t)(k0 + row) * N + n0 + c4);
    t[row][c4 + 0] = v.x; t[row][c4 + 1] = v.y;
    t[row][c4 + 2] = v.z; t[row][c4 + 3] = v.w;
  }
  __syncthreads();
#pragma unroll
  for (int i = 0; i < 2; ++i) {
    int c  = tid + i * 256;         // 0..511
    int n  = c >> 3;
    int k8 = (c & 7) * 8;
    union { u16 us[8]; uint4 v; } u;
#pragma unroll
    for (int j = 0; j < 8; ++j) u.us[j] = f2bf(t[k8 + j][n]);
    *(uint4*)(out + (size_t)(n0 + n) * K + k0 + k8) = u.v;
  }
}

// ---------------------------------------------------------------------------
// bf16 transpose: in [R,C] -> out [C,R]. 64x64 tiles.
// ---------------------------------------------------------------------------
__global__ __launch_bounds__(256)
void btrans(const u16* __restrict__ in, u16* __restrict__ out, int R, int C)
{
  __shared__ u16 t[64][72];         // 144B row stride, 16B aligned
  const int r0 = blockIdx.y * 64;
  const int c0 = blockIdx.x * 64;
  const int tid = threadIdx.x;
  const int r  = tid >> 3;          // 0..31
  const int c8 = (tid & 7) * 8;
#pragma unroll
  for (int i = 0; i < 2; ++i) {
    int row = r + i * 32;
    *(uint4*)&t[row][c8] = *(const uint4*)(in + (size_t)(r0 + row) * C + c0 + c8);
  }
  __syncthreads();
  const int cc = tid >> 3;          // 0..31
  const int r8 = (tid & 7) * 8;
#pragma unroll
  for (int i = 0; i < 2; ++i) {
    int ccol = cc + i * 32;
    union { u16 us[8]; uint4 v; } u;
#pragma unroll
    for (int j = 0; j < 8; ++j) u.us[j] = t[r8 + j][ccol];
    *(uint4*)(out + (size_t)(c0 + ccol) * R + r0 + r8) = u.v;
  }
}

// ---------------------------------------------------------------------------
// Embedding: x0[s,:] = token_emb[tok[s],:] + pos_emb[s,:]  (f32)
// ---------------------------------------------------------------------------
__global__ __launch_bounds__(256)
void embed_kernel(const int* __restrict__ tok, const float* __restrict__ temb,
                  const float* __restrict__ pemb, float* __restrict__ x)
{
  const int D = 2048;
  const int s = blockIdx.x;
  const int tid = threadIdx.x;
  const int tk = tok[s];
  const float* te = temb + (size_t)tk * D;
  const float* pe = pemb + (size_t)s * D;
  float* xr = x + (size_t)s * D;
#pragma unroll
  for (int i = 0; i < 2; ++i) {
    int o = tid * 8 + i * 4;
    float4 a = *(const float4*)(te + o);
    float4 b = *(const float4*)(pe + o);
    float4 c;
    c.x = a.x + b.x; c.y = a.y + b.y; c.z = a.z + b.z; c.w = a.w + b.w;
    *(float4*)(xr + o) = c;
  }
}

// ---------------------------------------------------------------------------
// LayerNorm: f32 in [rows, 2048] -> bf16 out. One block per row.
// ---------------------------------------------------------------------------
__global__ __launch_bounds__(256)
void ln_kernel(const float* __restrict__ x, const float* __restrict__ g,
               const float* __restrict__ b, u16* __restrict__ out)
{
  const int D = 2048;
  const int row = blockIdx.x;
  const int tid = threadIdx.x;
  const float* xr = x + (size_t)row * D;
  float4 v0 = *(const float4*)(xr + tid * 8);
  float4 v1 = *(const float4*)(xr + tid * 8 + 4);
  float s  = v0.x + v0.y + v0.z + v0.w + v1.x + v1.y + v1.z + v1.w;
  float q2 = v0.x * v0.x + v0.y * v0.y + v0.z * v0.z + v0.w * v0.w
           + v1.x * v1.x + v1.y * v1.y + v1.z * v1.z + v1.w * v1.w;
#pragma unroll
  for (int o = 32; o > 0; o >>= 1) {
    s  += __shfl_down(s, o);
    q2 += __shfl_down(q2, o);
  }
  __shared__ float ss[4], sq[4];
  if ((tid & 63) == 0) { ss[tid >> 6] = s; sq[tid >> 6] = q2; }
  __syncthreads();
  float S_ = ss[0] + ss[1] + ss[2] + ss[3];
  float Q_ = sq[0] + sq[1] + sq[2] + sq[3];
  float mean = S_ * (1.0f / D);
  float rstd = rsqrtf(Q_ * (1.0f / D) - mean * mean + 1e-5f);

  float4 g0 = *(const float4*)(g + tid * 8);
  float4 g1 = *(const float4*)(g + tid * 8 + 4);
  float4 b0 = *(const float4*)(b + tid * 8);
  float4 b1 = *(const float4*)(b + tid * 8 + 4);
  union { u16 us[8]; uint4 v; } u;
  u.us[0] = f2bf((v0.x - mean) * rstd * g0.x + b0.x);
  u.us[1] = f2bf((v0.y - mean) * rstd * g0.y + b0.y);
  u.us[2] = f2bf((v0.z - mean) * rstd * g0.z + b0.z);
  u.us[3] = f2bf((v0.w - mean) * rstd * g0.w + b0.w);
  u.us[4] = f2bf((v1.x - mean) * rstd * g1.x + b1.x);
  u.us[5] = f2bf((v1.y - mean) * rstd * g1.y + b1.y);
  u.us[6] = f2bf((v1.z - mean) * rstd * g1.z + b1.z);
  u.us[7] = f2bf((v1.w - mean) * rstd * g1.w + b1.w);
  *(uint4*)(out + (size_t)row * D + tid * 8) = u.v;
}

// ---------------------------------------------------------------------------
// Row softmax in place on bf16 [rows, 2048]. One block per row.
// ---------------------------------------------------------------------------
__global__ __launch_bounds__(256)
void softmax_kernel(u16* __restrict__ p)
{
  const int D = 2048;
  const size_t base = (size_t)blockIdx.x * D;
  const int tid = threadIdx.x;
  union { u16 us[8]; uint4 v; } u;
  u.v = *(const uint4*)(p + base + tid * 8);
  float f[8];
#pragma unroll
  for (int j = 0; j < 8; ++j) f[j] = bf2f(u.us[j]);
  float m = f[0];
#pragma unroll
  for (int j = 1; j < 8; ++j) m = fmaxf(m, f[j]);
#pragma unroll
  for (int o = 32; o > 0; o >>= 1) m = fmaxf(m, __shfl_xor(m, o));
  __shared__ float red[4], red2[4];
  if ((tid & 63) == 0) red[tid >> 6] = m;
  __syncthreads();
  m = fmaxf(fmaxf(red[0], red[1]), fmaxf(red[2], red[3]));
  float s = 0.0f;
#pragma unroll
  for (int j = 0; j < 8; ++j) { f[j] = __expf(f[j] - m); s += f[j]; }
#pragma unroll
  for (int o = 32; o > 0; o >>= 1) s += __shfl_xor(s, o);
  if ((tid & 63) == 0) red2[tid >> 6] = s;
  __syncthreads();
  s = red2[0] + red2[1] + red2[2] + red2[3];
  float inv = 1.0f / s;
#pragma unroll
  for (int j = 0; j < 8; ++j) u.us[j] = f2bf(f[j] * inv);
  *(uint4*)(p + base + tid * 8) = u.v;
}

// ---------------------------------------------------------------------------
extern "C" void kernel_launch(void* const* d_in, const int* in_sizes, int n_in,
                              void* d_out, int out_size, void* d_ws, size_t ws_size,
                              hipStream_t stream)
{
  (void)in_sizes; (void)n_in; (void)out_size; (void)ws_size;
  const int*   tokens = (const int*)  d_in[0];
  const float* temb   = (const float*)d_in[1];
  const float* pemb   = (const float*)d_in[2];
  const float* wq     = (const float*)d_in[3];
  const float* wk     = (const float*)d_in[4];
  const float* wv     = (const float*)d_in[5];
  const float* wo     = (const float*)d_in[6];
  const float* wfi    = (const float*)d_in[7];
  const float* wfo    = (const float*)d_in[8];
  const float* ln1g   = (const float*)d_in[9];
  const float* ln1b   = (const float*)d_in[10];
  const float* ln2g   = (const float*)d_in[11];
  const float* ln2b   = (const float*)d_in[12];
  const float* lnfg   = (const float*)d_in[13];
  const float* lnfb   = (const float*)d_in[14];
  const float* wout   = (const float*)d_in[15];

  constexpr int S = 2048, D = 2048, H = 16, HD = 128, FF = 8192, V = 32000;
  constexpr int HB = 8;  // heads per attention pass (score buffer = HB*S*S bf16)

  char* ws = (char*)d_ws;
  size_t off = 0;
  auto alloc = [&](size_t bytes) -> void* {
    void* pp = ws + off;
    off += (bytes + 255) & ~(size_t)255;
    return pp;
  };
  // total ws budget ~392 MB (was 634 MB in round 0 — possible ws overflow)
  u16*   wqkvT  = (u16*)  alloc((size_t)3 * D * D * 2);   // [3][D,D] (N,K)  25.2MB
  u16*   woT    = (u16*)  alloc((size_t)D * D * 2);       //                  8.4MB
  u16*   wfiT   = (u16*)  alloc((size_t)D * FF * 2);      // [FF, D]         33.6MB
  u16*   wfoT   = (u16*)  alloc((size_t)D * FF * 2);      // [D, FF]         33.6MB
  u16*   woutT  = (u16*)  alloc((size_t)D * V * 2);       // [V, D]         131.1MB
  float* x0     = (float*)alloc((size_t)S * D * 4);       //                 16.8MB
  float* x1     = (float*)alloc((size_t)S * D * 4);       //                 16.8MB
  u16*   hbuf   = (u16*)  alloc((size_t)S * D * 2);       //                  8.4MB
  u16*   qkv    = (u16*)  alloc((size_t)3 * S * D * 2);   //                 25.2MB
  u16*   vt     = (u16*)  alloc((size_t)S * D * 2);       // [D, S]           8.4MB
  u16*   attn   = (u16*)  alloc((size_t)S * D * 2);       //                  8.4MB
  u16*   scores = (u16*)  alloc((size_t)HB * S * S * 2);  // [HB, S, S]      67.1MB
  u16*   ff1    = scores;                                  // reuse: scores dead after attn
  float* x2     = x0;                                      // reuse: x0 dead after wo-gemm

  dim3 b256(256);

  // weight convert+transpose (re-done every call; ws is re-poisoned)
  wtrans<<<dim3(D / 64, D / 64), b256, 0, stream>>>(wq, wqkvT + 0 * (size_t)D * D, D, D);
  wtrans<<<dim3(D / 64, D / 64), b256, 0, stream>>>(wk, wqkvT + 1 * (size_t)D * D, D, D);
  wtrans<<<dim3(D / 64, D / 64), b256, 0, stream>>>(wv, wqkvT + 2 * (size_t)D * D, D, D);
  wtrans<<<dim3(D / 64, D / 64), b256, 0, stream>>>(wo, woT, D, D);
  wtrans<<<dim3(FF / 64, D / 64), b256, 0, stream>>>(wfi, wfiT, D, FF);
  wtrans<<<dim3(D / 64, FF / 64), b256, 0, stream>>>(wfo, wfoT, FF, D);
  wtrans<<<dim3(V / 64, D / 64), b256, 0, stream>>>(wout, woutT, D, V);

  embed_kernel<<<S, b256, 0, stream>>>(tokens, temb, pemb, x0);
  ln_kernel<<<S, b256, 0, stream>>>(x0, ln1g, ln1b, hbuf);

  // q,k,v = h @ {wq,wk,wv} : batched z=3, out bf16 [3][S,D]
  gemm_bt<true, false, false><<<dim3(D / 128, S / 128, 3), b256, 0, stream>>>(
      hbuf, wqkvT, qkv, nullptr, 1.0f, S, D, D, D, D, D,
      0LL, (long long)D * D, (long long)S * D);

  u16* q = qkv;
  u16* k = qkv + (size_t)S * D;
  u16* v = qkv + 2 * (size_t)S * D;

  btrans<<<dim3(D / 64, S / 64), b256, 0, stream>>>(v, vt, S, D);

  // attention in two passes of HB=8 heads, reusing one [HB,S,S] score buffer
  for (int p = 0; p < H / HB; ++p) {
    const u16* qp = q + (size_t)p * HB * HD;
    const u16* kp = k + (size_t)p * HB * HD;
    const u16* vp = vt + (size_t)p * HB * HD * S;
    u16* ap = attn + (size_t)p * HB * HD;

    // scores[h] = (q_h @ k_h^T) / sqrt(hd)
    gemm_bt<true, false, false><<<dim3(S / 128, S / 128, HB), b256, 0, stream>>>(
        qp, kp, scores, nullptr, 0.08838834764831845f, S, S, HD, D, D, S,
        (long long)HD, (long long)HD, (long long)S * S);

    softmax_kernel<<<HB * S, b256, 0, stream>>>(scores);

    // attn[:, head cols] = probs_h @ v_h : Bt = vt_h [HD, S]
    gemm_bt<true, false, false><<<dim3(HD / 128, S / 128, HB), b256, 0, stream>>>(
        scores, vp, ap, nullptr, 1.0f, S, HD, S, S, S, D,
        (long long)S * S, (long long)HD * S, (long long)HD);
  }

  // x1 = x0 + attn @ wo   (f32 out)
  gemm_bt<false, false, true><<<dim3(D / 128, S / 128, 1), b256, 0, stream>>>(
      attn, woT, x1, x0, 1.0f, S, D, D, D, D, D, 0LL, 0LL, 0LL);

  ln_kernel<<<S, b256, 0, stream>>>(x1, ln2g, ln2b, hbuf);

  // ff1 = relu(h @ w_ff_in)  (bf16)
  gemm_bt<true, true, false><<<dim3(FF / 128, S / 128, 1), b256, 0, stream>>>(
      hbuf, wfiT, ff1, nullptr, 1.0f, S, FF, D, D, D, FF, 0LL, 0LL, 0LL);

  // x2 = x1 + ff1 @ w_ff_out  (f32)
  gemm_bt<false, false, true><<<dim3(D / 128, S / 128, 1), b256, 0, stream>>>(
      ff1, wfoT, x2, x1, 1.0f, S, D, FF, FF, FF, D, 0LL, 0LL, 0LL);

  ln_kernel<<<S, b256, 0, stream>>>(x2, lnfg, lnfb, hbuf);

  // logits = h @ w_out  (f32, straight to d_out)
  gemm_bt<false, false, false><<<dim3(V / 128, S / 128, 1), b256, 0, stream>>>(
      hbuf, woutT, (float*)d_out, nullptr, 1.0f, S, V, D, D, D, V, 0LL, 0LL, 0LL);
}